// Round 9
// baseline (290.166 us; speedup 1.0000x reference)
//
#include <hip/hip_runtime.h>
#include <hip/hip_cooperative_groups.h>

namespace cg = cooperative_groups;

#define NUM_JOINTS 24
#define NUM_VERTS  6890
#define NUM_COORDS (NUM_VERTS * 3)   // 20670
#define NUM_BETAS  10
#define KTOT       217               // 10 betas + 207 pose features
#define KPAD       224               // padded K for MFMA (7 x 32)
#define BATCH      512
#define VPAD       6912              // padded vertex count

// ---- ws layout (float offsets); ushort regions: floats = ushorts/2 ----
#define WS_SJ   0          //    720: SJ[k][j][c]
#define WS_JT   720        //     72: JT[j][c]                      (pad to 800)
#define WS_XBF  800        //  57344: ushort 512 x 224
#define WS_DBF  58144      // 2322432: ushort 20736 x 224
#define WS_WHBF 2380576    // 110592: ushort 6912 x 32
#define WS_AH   2491168    // 131072: ushort 8192 x 32
#define WS_AL   2622240    // 131072: ushort 8192 x 32  -> total ~11 MB

typedef __attribute__((ext_vector_type(8))) short short8;
typedef __attribute__((ext_vector_type(4))) float f32x4;

__device__ inline unsigned short f2bf(float f) {
    union { float f; unsigned u; } c; c.f = f;
    unsigned u = c.u;
    u += 0x7fffu + ((u >> 16) & 1u);   // RNE
    return (unsigned short)(u >> 16);
}
__device__ inline float bf2f(unsigned short h) {
    union { unsigned u; float f; } c; c.u = ((unsigned)h) << 16;
    return c.f;
}

struct PBShm {
    float Rs[4][24][9];
    float Jl[4][24][3];
    float Rg[4][24][9];
    float tg[4][24][3];
    float As[4][24][12];
};   // 13824 B

// ================= tile bodies (shared by mega and fallback kernels) =================

// t in [0,900): 0..26 prep whbf, 27..107 convert dbf, 108..899 reduce SJ/JT
__device__ __forceinline__ void tile_prep(int t, int tid,
                                          const float* __restrict__ Jr,
                                          const float* __restrict__ sd,
                                          const float* __restrict__ pd,
                                          const float* __restrict__ vt,
                                          const float* __restrict__ w,
                                          unsigned short* __restrict__ whbf,
                                          unsigned short* __restrict__ dbf,
                                          float* __restrict__ ws,
                                          float* red) {
    if (t < 27) {
        const int v = t * 256 + tid;      // < 6912
        const bool ok = (v < NUM_VERTS);
        unsigned short row[32];
        #pragma unroll
        for (int j = 0; j < 32; ++j)
            row[j] = f2bf((ok && j < 24) ? w[v * 24 + j] : 0.f);
        #pragma unroll
        for (int i = 0; i < 4; ++i)
            *(float4*)(whbf + (size_t)v * 32 + i * 8) = *(const float4*)(&row[i * 8]);
    } else if (t < 108) {
        const int c = (t - 27) * 256 + tid;   // < 20736
        const bool valid = (c < NUM_COORDS);
        unsigned short* drow = dbf + (size_t)c * KPAD;
        for (int g = 0; g < 4; ++g) {
            unsigned buf[28];
            #pragma unroll
            for (int h = 0; h < 28; ++h) {
                const int k0 = g * 56 + 2 * h;
                const int k1 = k0 + 1;
                float v0 = 0.f, v1 = 0.f;
                if (valid) {
                    v0 = (k0 < 10) ? sd[(size_t)k0 * NUM_COORDS + c]
                       : (k0 < KTOT) ? pd[(size_t)(k0 - 10) * NUM_COORDS + c] : 0.f;
                    v1 = (k1 < 10) ? sd[(size_t)k1 * NUM_COORDS + c]
                       : (k1 < KTOT) ? pd[(size_t)(k1 - 10) * NUM_COORDS + c] : 0.f;
                }
                buf[h] = (unsigned)f2bf(v0) | ((unsigned)f2bf(v1) << 16);
            }
            #pragma unroll
            for (int h = 0; h < 7; ++h)
                *(float4*)(drow + g * 56 + h * 8) = *(const float4*)(&buf[h * 4]);
        }
    } else {
        const int u = t - 108;
        const int s = u % 33;    // 0..32
        const int j = u / 33;    // 0..23
        float sum = 0.f;
        if (s < 30) {
            const int k = s / 3, c = s % 3;
            const float* src = sd + (size_t)k * NUM_COORDS;
            for (int v = tid; v < NUM_VERTS; v += 256)
                sum += Jr[v * 24 + j] * src[v * 3 + c];
        } else {
            const int c = s - 30;
            for (int v = tid; v < NUM_VERTS; v += 256)
                sum += Jr[v * 24 + j] * vt[v * 3 + c];
        }
        red[tid] = sum;
        __syncthreads();
        for (int off = 128; off > 0; off >>= 1) {
            if (tid < off) red[tid] += red[tid + off];
            __syncthreads();
        }
        if (tid == 0) {
            if (s < 30) ws[WS_SJ + (s / 3) * 72 + j * 3 + (s % 3)] = red[0];
            else        ws[WS_JT + j * 3 + (s - 30)] = red[0];
        }
        __syncthreads();
    }
}

// t in [0,128): 4 batches per tile (sub = tid>>6)
__device__ __forceinline__ void tile_pb(int t, int tid,
                                        const float* __restrict__ x,
                                        const int* __restrict__ parents,
                                        float* __restrict__ ws,
                                        unsigned short* __restrict__ ahi,
                                        unsigned short* __restrict__ alo,
                                        unsigned short* __restrict__ xbf,
                                        PBShm* Pp) {
    PBShm& P = *Pp;
    const int sub  = tid >> 6;
    const int lane = tid & 63;
    const int b = t * 4 + sub;
    const float* row = x + b * (NUM_BETAS + 72);

    if (lane < 24) {
        const int j = lane;
        const float t0 = row[3 * j + 0], t1 = row[3 * j + 1], t2 = row[3 * j + 2];
        const float a0 = t0 + 1e-8f, a1 = t1 + 1e-8f, a2 = t2 + 1e-8f;
        const float angle = sqrtf(a0 * a0 + a1 * a1 + a2 * a2);
        const float inv = 1.0f / angle;
        const float rx = t0 * inv, ry = t1 * inv, rz = t2 * inv;
        const float c = cosf(angle), sn = sinf(angle), o = 1.f - c;
        float R[9];
        R[0] = c + o * rx * rx;       R[1] = o * rx * ry - sn * rz; R[2] = o * rx * rz + sn * ry;
        R[3] = o * rx * ry + sn * rz; R[4] = c + o * ry * ry;       R[5] = o * ry * rz - sn * rx;
        R[6] = o * rx * rz - sn * ry; R[7] = o * ry * rz + sn * rx; R[8] = c + o * rz * rz;
        #pragma unroll
        for (int i = 0; i < 9; ++i) P.Rs[sub][j][i] = R[i];
        #pragma unroll
        for (int c3 = 0; c3 < 3; ++c3) {
            float s = ws[WS_JT + j * 3 + c3];
            #pragma unroll
            for (int k = 0; k < NUM_BETAS; ++k)
                s += row[72 + k] * ws[WS_SJ + k * 72 + j * 3 + c3];
            P.Jl[sub][j][c3] = s;
        }
        if (j >= 1) {
            #pragma unroll
            for (int i = 0; i < 9; ++i) {
                const float pf = R[i] - ((i == 0 || i == 4 || i == 8) ? 1.f : 0.f);
                xbf[(size_t)b * KPAD + 10 + (j - 1) * 9 + i] = f2bf(pf);
            }
        }
    }
    if (lane < NUM_BETAS) xbf[(size_t)b * KPAD + lane] = f2bf(row[72 + lane]);
    if (lane == 63) {
        #pragma unroll
        for (int k = KTOT; k < KPAD; ++k) xbf[(size_t)b * KPAD + k] = 0;
    }
    __syncthreads();

    if (lane == 0) {
        #pragma unroll
        for (int i = 0; i < 9; ++i) P.Rg[sub][0][i] = P.Rs[sub][0][i];
        #pragma unroll
        for (int c3 = 0; c3 < 3; ++c3) P.tg[sub][0][c3] = P.Jl[sub][0][c3];
        for (int i = 1; i < 24; ++i) {
            const int p = parents[i];
            float tmp[9];
            #pragma unroll
            for (int r = 0; r < 3; ++r)
                #pragma unroll
                for (int cc = 0; cc < 3; ++cc)
                    tmp[r * 3 + cc] = P.Rg[sub][p][r * 3 + 0] * P.Rs[sub][i][0 + cc] +
                                      P.Rg[sub][p][r * 3 + 1] * P.Rs[sub][i][3 + cc] +
                                      P.Rg[sub][p][r * 3 + 2] * P.Rs[sub][i][6 + cc];
            #pragma unroll
            for (int q = 0; q < 9; ++q) P.Rg[sub][i][q] = tmp[q];
            const float tr0 = P.Jl[sub][i][0] - P.Jl[sub][p][0];
            const float tr1 = P.Jl[sub][i][1] - P.Jl[sub][p][1];
            const float tr2 = P.Jl[sub][i][2] - P.Jl[sub][p][2];
            #pragma unroll
            for (int r = 0; r < 3; ++r)
                P.tg[sub][i][r] = P.Rg[sub][p][r * 3 + 0] * tr0 + P.Rg[sub][p][r * 3 + 1] * tr1 +
                                  P.Rg[sub][p][r * 3 + 2] * tr2 + P.tg[sub][p][r];
        }
    }
    __syncthreads();

    if (lane < 24) {
        const int j = lane;
        #pragma unroll
        for (int r = 0; r < 3; ++r) {
            const float tt = P.tg[sub][j][r] - (P.Rg[sub][j][r * 3 + 0] * P.Jl[sub][j][0] +
                                                P.Rg[sub][j][r * 3 + 1] * P.Jl[sub][j][1] +
                                                P.Rg[sub][j][r * 3 + 2] * P.Jl[sub][j][2]);
            P.As[sub][j][r * 4 + 0] = P.Rg[sub][j][r * 3 + 0];
            P.As[sub][j][r * 4 + 1] = P.Rg[sub][j][r * 3 + 1];
            P.As[sub][j][r * 4 + 2] = P.Rg[sub][j][r * 3 + 2];
            P.As[sub][j][r * 4 + 3] = tt;
        }
    }
    __syncthreads();

    if (lane < 32) {
        const int r = lane >> 1;     // pq row 0..15
        const int half = lane & 1;   // k half
        unsigned short hi[16], lo[16];
        #pragma unroll
        for (int i = 0; i < 16; ++i) {
            const int j = half * 16 + i;
            float v = 0.f;
            if (r < 12 && j < 24) v = P.As[sub][j][r];
            const unsigned short h = f2bf(v);
            hi[i] = h;
            lo[i] = f2bf(v - bf2f(h));
        }
        unsigned short* dh = ahi + ((size_t)b * 16 + r) * 32 + half * 16;
        unsigned short* dl = alo + ((size_t)b * 16 + r) * 32 + half * 16;
        #pragma unroll
        for (int i = 0; i < 2; ++i) {
            *(float4*)(dh + i * 8) = *(const float4*)(&hi[i * 8]);
            *(float4*)(dl + i * 8) = *(const float4*)(&lo[i * 8]);
        }
    }
    __syncthreads();
}

// txx in [0,323), tyy in [0,4): r7 gemm body
__device__ __forceinline__ void tile_gemm(int txx, int tyy, int tid,
                                          const unsigned short* __restrict__ dbf,
                                          const unsigned short* __restrict__ xbf,
                                          const float* __restrict__ vt,
                                          float* __restrict__ out,
                                          unsigned short* Xs) {
    const int wave = tid >> 6;
    const int lane = tid & 63;
    const int col  = lane & 15;
    const int quad = lane >> 4;
    const int n0   = txx * 64;
    const int nc   = n0 + wave * 16 + col;

    short8 bfrag[7];
    {
        const unsigned short* brow = dbf + (size_t)nc * KPAD + quad * 8;
        #pragma unroll
        for (int kb = 0; kb < 7; ++kb)
            bfrag[kb] = *(const short8*)(brow + kb * 32);
    }
    const float vtl = (nc < NUM_COORDS) ? vt[nc] : 0.f;
    const bool nok = (nc < NUM_COORDS);

    for (int chunk = 0; chunk < 2; ++chunk) {
        const int m0 = tyy * 128 + chunk * 64;
        __syncthreads();
        #pragma unroll
        for (int i = 0; i < 7; ++i) {
            const int c = tid + i * 256;
            const int r = c / 28;
            const int off = c % 28;
            const float4 v = *(const float4*)(xbf + (size_t)(m0 + r) * KPAD + off * 8);
            *(float4*)(&Xs[r * 232 + off * 8]) = v;
        }
        __syncthreads();

        #pragma unroll
        for (int mt = 0; mt < 4; ++mt) {
            const unsigned short* arow = &Xs[(mt * 16 + col) * 232 + quad * 8];
            f32x4 acc = {0.f, 0.f, 0.f, 0.f};
            #pragma unroll
            for (int kb = 0; kb < 7; ++kb) {
                const short8 afrag = *(const short8*)(arow + kb * 32);
                acc = __builtin_amdgcn_mfma_f32_16x16x32_bf16(afrag, bfrag[kb], acc, 0, 0, 0);
            }
            if (nok) {
                float* base = out + (size_t)(m0 + mt * 16 + quad * 4) * NUM_COORDS + nc;
                base[0]                       = acc[0] + vtl;
                base[(size_t)NUM_COORDS]      = acc[1] + vtl;
                base[(size_t)2 * NUM_COORDS]  = acc[2] + vtl;
                base[(size_t)3 * NUM_COORDS]  = acc[3] + vtl;
            }
        }
    }
    __syncthreads();
}

// txx in [0,108), tyy in [0,16): r7 skin body
__device__ __forceinline__ void tile_skin(int txx, int tyy, int tid,
                                          const unsigned short* __restrict__ whbf,
                                          const unsigned short* __restrict__ ahi,
                                          const unsigned short* __restrict__ alo,
                                          float* __restrict__ out,
                                          float* Tsf) {
    const int wave = tid >> 6;
    const int lane = tid & 63;
    const int col  = lane & 15;
    const int quad = lane >> 4;
    const int v0   = txx * 64;
    const int b0   = tyy * 32;
    float* ts = Tsf + wave * (64 * 17);

    short8 wfrag[4];
    #pragma unroll
    for (int mt = 0; mt < 4; ++mt)
        wfrag[mt] = *(const short8*)(whbf + (size_t)(v0 + mt * 16 + col) * 32 + quad * 8);

    const int vv = v0 + lane;
    const bool vok = (vv < NUM_VERTS);

    for (int nt = wave; nt < 32; nt += 4) {
        const int b = b0 + nt;
        float* orow = out + (size_t)b * NUM_COORDS + (size_t)vv * 3;
        float h0 = 0.f, h1 = 0.f, h2 = 0.f;
        if (vok) { h0 = orow[0]; h1 = orow[1]; h2 = orow[2]; }

        const short8 bh = *(const short8*)(ahi + ((size_t)b * 16 + col) * 32 + quad * 8);
        const short8 bl = *(const short8*)(alo + ((size_t)b * 16 + col) * 32 + quad * 8);

        f32x4 acc[4];
        #pragma unroll
        for (int mt = 0; mt < 4; ++mt) {
            f32x4 z = {0.f, 0.f, 0.f, 0.f};
            z = __builtin_amdgcn_mfma_f32_16x16x32_bf16(wfrag[mt], bh, z, 0, 0, 0);
            z = __builtin_amdgcn_mfma_f32_16x16x32_bf16(wfrag[mt], bl, z, 0, 0, 0);
            acc[mt] = z;
        }
        #pragma unroll
        for (int mt = 0; mt < 4; ++mt)
            #pragma unroll
            for (int r = 0; r < 4; ++r)
                ts[(mt * 16 + quad * 4 + r) * 17 + col] = acc[mt][r];

        float Tp[12];
        #pragma unroll
        for (int i = 0; i < 12; ++i) Tp[i] = ts[lane * 17 + i];

        if (vok) {
            const float o0 = Tp[0] * h0 + Tp[1] * h1 + Tp[2]  * h2 + Tp[3];
            const float o1 = Tp[4] * h0 + Tp[5] * h1 + Tp[6]  * h2 + Tp[7];
            const float o2 = Tp[8] * h0 + Tp[9] * h1 + Tp[10] * h2 + Tp[11];
            orow[0] = o0; orow[1] = o1; orow[2] = o2;
        }
    }
}

// ================= mega cooperative kernel =================
__global__ __launch_bounds__(256) void mega(const float* __restrict__ x,
                                            const float* __restrict__ vt,
                                            const float* __restrict__ sd,
                                            const float* __restrict__ Jr,
                                            const float* __restrict__ pd,
                                            const float* __restrict__ w,
                                            const int* __restrict__ parents,
                                            float* __restrict__ out,
                                            float* __restrict__ ws) {
    __shared__ __align__(16) unsigned char smem[29696];
    unsigned short* xbf  = (unsigned short*)(ws + WS_XBF);
    unsigned short* dbf  = (unsigned short*)(ws + WS_DBF);
    unsigned short* whbf = (unsigned short*)(ws + WS_WHBF);
    unsigned short* ahi  = (unsigned short*)(ws + WS_AH);
    unsigned short* alo  = (unsigned short*)(ws + WS_AL);

    cg::grid_group grid = cg::this_grid();
    const int tid = threadIdx.x;
    const int bx  = blockIdx.x;
    const int GS  = gridDim.x;

    for (int t = bx; t < 900; t += GS)
        tile_prep(t, tid, Jr, sd, pd, vt, w, whbf, dbf, ws, (float*)smem);
    grid.sync();
    for (int t = bx; t < 128; t += GS)
        tile_pb(t, tid, x, parents, ws, ahi, alo, xbf, (PBShm*)smem);
    grid.sync();
    for (int t = bx; t < 1292; t += GS)
        tile_gemm(t % 323, t / 323, tid, dbf, xbf, vt, out, (unsigned short*)smem);
    grid.sync();
    for (int t = bx; t < 1728; t += GS)
        tile_skin(t % 108, t / 108, tid, whbf, ahi, alo, out, (float*)smem);
}

// ================= fallback standalone kernels =================
__global__ __launch_bounds__(256) void k_prep(const float* __restrict__ Jr,
                                              const float* __restrict__ sd,
                                              const float* __restrict__ pd,
                                              const float* __restrict__ vt,
                                              const float* __restrict__ w,
                                              float* __restrict__ ws) {
    __shared__ float red[256];
    tile_prep(blockIdx.x, threadIdx.x, Jr, sd, pd, vt, w,
              (unsigned short*)(ws + WS_WHBF), (unsigned short*)(ws + WS_DBF), ws, red);
}

__global__ __launch_bounds__(256) void k_pb(const float* __restrict__ x,
                                            const int* __restrict__ parents,
                                            float* __restrict__ ws) {
    __shared__ PBShm P;
    tile_pb(blockIdx.x, threadIdx.x, x, parents, ws,
            (unsigned short*)(ws + WS_AH), (unsigned short*)(ws + WS_AL),
            (unsigned short*)(ws + WS_XBF), &P);
}

__global__ __launch_bounds__(256) void k_gemm(const float* __restrict__ vt,
                                              float* __restrict__ out,
                                              float* __restrict__ ws) {
    __shared__ __align__(16) unsigned short Xs[64 * 232];
    tile_gemm(blockIdx.x, blockIdx.y, threadIdx.x,
              (unsigned short*)(ws + WS_DBF), (unsigned short*)(ws + WS_XBF), vt, out, Xs);
}

__global__ __launch_bounds__(256) void k_skin(float* __restrict__ out,
                                              float* __restrict__ ws) {
    __shared__ float Ts[4 * 64 * 17];
    tile_skin(blockIdx.x, blockIdx.y, threadIdx.x,
              (unsigned short*)(ws + WS_WHBF), (unsigned short*)(ws + WS_AH),
              (unsigned short*)(ws + WS_AL), out, Ts);
}

extern "C" void kernel_launch(void* const* d_in, const int* in_sizes, int n_in,
                              void* d_out, int out_size, void* d_ws, size_t ws_size,
                              hipStream_t stream) {
    const float* x  = (const float*)d_in[0];
    const float* vt = (const float*)d_in[1];
    const float* sd = (const float*)d_in[2];
    const float* Jr = (const float*)d_in[3];
    const float* pd = (const float*)d_in[4];
    const float* w  = (const float*)d_in[5];
    const int* parents = (const int*)d_in[6];
    float* out = (float*)d_out;
    float* ws  = (float*)d_ws;

    // Occupancy-adapted cooperative grid (host-side queries: capture-safe)
    int dev = 0;
    hipGetDevice(&dev);
    int coop = 0;
    hipDeviceGetAttribute(&coop, hipDeviceAttributeCooperativeLaunch, dev);
    int nb = 0;
    hipOccupancyMaxActiveBlocksPerMultiprocessor(&nb, reinterpret_cast<const void*>(mega), 256, 0);

    bool launched = false;
    if (coop && nb > 0) {
        int gridsz = nb * 256;
        if (gridsz > 1024) gridsz = 1024;
        void* kargs[] = {(void*)&x, (void*)&vt, (void*)&sd, (void*)&Jr, (void*)&pd,
                         (void*)&w, (void*)&parents, (void*)&out, (void*)&ws};
        hipError_t e = hipLaunchCooperativeKernel(reinterpret_cast<void*>(mega),
                                                  dim3(gridsz), dim3(256), kargs, 0, stream);
        launched = (e == hipSuccess);
    }
    if (!launched) {
        k_prep<<<900, 256, 0, stream>>>(Jr, sd, pd, vt, w, ws);
        k_pb  <<<128, 256, 0, stream>>>(x, parents, ws);
        k_gemm<<<dim3(323, 4), 256, 0, stream>>>(vt, out, ws);
        k_skin<<<dim3(108, 16), 256, 0, stream>>>(out, ws);
    }
}

// Round 10
// 163.225 us; speedup vs baseline: 1.7777x; 1.7777x over previous
//
#include <hip/hip_runtime.h>

#define NUM_JOINTS 24
#define NUM_VERTS  6890
#define NUM_COORDS (NUM_VERTS * 3)   // 20670
#define NUM_BETAS  10
#define KTOT       217               // 10 betas + 207 pose features
#define KPAD       224               // padded K for MFMA (7 x 32)
#define BATCH      512
#define VPAD       6912              // padded vertex count

// ---- ws layout (float offsets); ushort regions: floats = ushorts/2 ----
#define WS_SJP  0          //  85536: float 108 strips x 792 partials (s*24+j, s=src 0..32)
#define WS_XBF  85536      //  57344: ushort 512 x 224
#define WS_DBF  142880     // 2322432: ushort 20736 x 224
#define WS_WHBF 2465312    // 110592: ushort 6912 x 32
#define WS_AH   2575904    // 131072: ushort 8192 x 32
#define WS_AL   2706976    // 131072: ushort 8192 x 32  -> total 2838048 floats ~11.4 MB

typedef __attribute__((ext_vector_type(8))) short short8;
typedef __attribute__((ext_vector_type(4))) float f32x4;

__device__ inline unsigned short f2bf(float f) {
    union { float f; unsigned u; } c; c.f = f;
    unsigned u = c.u;
    u += 0x7fffu + ((u >> 16) & 1u);   // RNE
    return (unsigned short)(u >> 16);
}
__device__ inline float bf2f(unsigned short h) {
    union { unsigned u; float f; } c; c.u = ((unsigned)h) << 16;
    return c.f;
}

struct PBShm {
    float Rs[4][24][9];
    float Jl[4][24][3];
    float Rg[4][24][9];
    float tg[4][24][3];
    float As[4][24][12];
};   // 13824 B

// ================= k_prep: 459 blocks =================
// t 0..26:   Whbf[6912][32] bf16 rows
// t 27..350: D^T transpose via LDS (64 coords x 224 k per block, coalesced both sides)
// t 351..458: SJ strip partials (64 verts per strip, all 33 sources x 24 joints)
__global__ __launch_bounds__(256) void k_prep(const float* __restrict__ Jr,
                                              const float* __restrict__ sd,
                                              const float* __restrict__ pd,
                                              const float* __restrict__ vt,
                                              const float* __restrict__ w,
                                              float* __restrict__ ws) {
    __shared__ __align__(16) unsigned char smem[28928];
    const int t   = blockIdx.x;
    const int tid = threadIdx.x;
    unsigned short* whbf = (unsigned short*)(ws + WS_WHBF);
    unsigned short* dbf  = (unsigned short*)(ws + WS_DBF);

    if (t < 27) {
        const int v = t * 256 + tid;      // < 6912
        const bool ok = (v < NUM_VERTS);
        unsigned short row[32];
        #pragma unroll
        for (int j = 0; j < 32; ++j)
            row[j] = f2bf((ok && j < 24) ? w[v * 24 + j] : 0.f);
        #pragma unroll
        for (int i = 0; i < 4; ++i)
            *(float4*)(whbf + (size_t)v * 32 + i * 8) = *(const float4*)(&row[i * 8]);
    } else if (t < 351) {
        // ---- D^T transpose: block covers coords c0..c0+63, k 0..223 ----
        unsigned* L = (unsigned*)smem;        // [64][113] dwords (stride 113: odd -> conflict-free)
        const int c0   = (t - 27) * 64;
        const int lane = tid & 63;
        const int grp  = tid >> 6;
        const int c    = c0 + lane;
        const bool cv  = (c < NUM_COORDS);
        #pragma unroll 4
        for (int i = 0; i < 28; ++i) {
            const int p  = i * 4 + grp;       // dword-pair 0..111
            const int k0 = 2 * p, k1 = k0 + 1;
            float v0 = 0.f, v1 = 0.f;
            if (cv) {
                v0 = (k0 < 10) ? sd[(size_t)k0 * NUM_COORDS + c]
                   : (k0 < KTOT) ? pd[(size_t)(k0 - 10) * NUM_COORDS + c] : 0.f;
                v1 = (k1 < 10) ? sd[(size_t)k1 * NUM_COORDS + c]
                   : (k1 < KTOT) ? pd[(size_t)(k1 - 10) * NUM_COORDS + c] : 0.f;
            }
            L[lane * 113 + p] = (unsigned)f2bf(v0) | ((unsigned)f2bf(v1) << 16);
        }
        __syncthreads();
        #pragma unroll
        for (int i = 0; i < 7; ++i) {
            const int idx = i * 256 + tid;    // < 1792
            const int row = idx / 28;
            const int q   = idx % 28;
            uint4 val;
            val.x = L[row * 113 + q * 4 + 0];
            val.y = L[row * 113 + q * 4 + 1];
            val.z = L[row * 113 + q * 4 + 2];
            val.w = L[row * 113 + q * 4 + 3];
            *(uint4*)(dbf + (size_t)(c0 + row) * KPAD + q * 8) = val;
        }
    } else {
        // ---- SJ strip partials ----
        float* Jl = (float*)smem;                 // [64][25]
        float* S  = (float*)smem + 64 * 25;       // [33][64]
        const int strip = t - 351;
        const int v0 = strip * 64;
        #pragma unroll
        for (int i = 0; i < 6; ++i) {
            const int idx = i * 256 + tid;        // < 1536
            const int v = idx / 24, j = idx % 24;
            Jl[v * 25 + j] = (v0 + v < NUM_VERTS) ? Jr[(size_t)(v0 + v) * 24 + j] : 0.f;
        }
        #pragma unroll
        for (int i = 0; i < 9; ++i) {
            const int idx = i * 256 + tid;
            if (idx < 33 * 64) {
                const int s = idx / 64, v = idx % 64;
                float val = 0.f;
                if (v0 + v < NUM_VERTS) {
                    if (s < 30) val = sd[(size_t)(s / 3) * NUM_COORDS + (size_t)(v0 + v) * 3 + (s % 3)];
                    else        val = vt[(size_t)(v0 + v) * 3 + (s - 30)];
                }
                S[s * 64 + v] = val;
            }
        }
        __syncthreads();
        float* wsp = ws + WS_SJP + (size_t)strip * 792;
        for (int o = tid; o < 792; o += 256) {
            const int s = o / 24, j = o % 24;
            float sum = 0.f;
            #pragma unroll 8
            for (int v = 0; v < 64; ++v)
                sum += S[s * 64 + v] * Jl[v * 25 + j];
            wsp[o] = sum;
        }
    }
}

// ================= k_pb: 128 blocks x 4 batches (r9-verified body + SJ prologue) =================
__global__ __launch_bounds__(256) void k_pb(const float* __restrict__ x,
                                            const int* __restrict__ parents,
                                            float* __restrict__ ws) {
    __shared__ PBShm P;
    __shared__ float SJf[792];        // [s=src 0..32][j]: s<30 -> SJ(k=s/3, c=s%3); s>=30 -> JT(c=s-30)
    unsigned short* xbf = (unsigned short*)(ws + WS_XBF);
    unsigned short* ahi = (unsigned short*)(ws + WS_AH);
    unsigned short* alo = (unsigned short*)(ws + WS_AL);
    const int tid = threadIdx.x;

    {   // sum strip partials -> SJf
        const float* wsp = ws + WS_SJP;
        for (int o = tid; o < 792; o += 256) {
            float sum = 0.f;
            for (int s2 = 0; s2 < 108; ++s2)
                sum += wsp[(size_t)s2 * 792 + o];
            SJf[o] = sum;
        }
    }
    __syncthreads();

    const int sub  = tid >> 6;
    const int lane = tid & 63;
    const int b = blockIdx.x * 4 + sub;
    const float* row = x + b * (NUM_BETAS + 72);

    if (lane < 24) {
        const int j = lane;
        const float t0 = row[3 * j + 0], t1 = row[3 * j + 1], t2 = row[3 * j + 2];
        const float a0 = t0 + 1e-8f, a1 = t1 + 1e-8f, a2 = t2 + 1e-8f;
        const float angle = sqrtf(a0 * a0 + a1 * a1 + a2 * a2);
        const float inv = 1.0f / angle;
        const float rx = t0 * inv, ry = t1 * inv, rz = t2 * inv;
        const float c = cosf(angle), sn = sinf(angle), o = 1.f - c;
        float R[9];
        R[0] = c + o * rx * rx;       R[1] = o * rx * ry - sn * rz; R[2] = o * rx * rz + sn * ry;
        R[3] = o * rx * ry + sn * rz; R[4] = c + o * ry * ry;       R[5] = o * ry * rz - sn * rx;
        R[6] = o * rx * rz - sn * ry; R[7] = o * ry * rz + sn * rx; R[8] = c + o * rz * rz;
        #pragma unroll
        for (int i = 0; i < 9; ++i) P.Rs[sub][j][i] = R[i];
        #pragma unroll
        for (int c3 = 0; c3 < 3; ++c3) {
            float s = SJf[(30 + c3) * 24 + j];
            #pragma unroll
            for (int k = 0; k < NUM_BETAS; ++k)
                s += row[72 + k] * SJf[(k * 3 + c3) * 24 + j];
            P.Jl[sub][j][c3] = s;
        }
        if (j >= 1) {
            #pragma unroll
            for (int i = 0; i < 9; ++i) {
                const float pf = R[i] - ((i == 0 || i == 4 || i == 8) ? 1.f : 0.f);
                xbf[(size_t)b * KPAD + 10 + (j - 1) * 9 + i] = f2bf(pf);
            }
        }
    }
    if (lane < NUM_BETAS) xbf[(size_t)b * KPAD + lane] = f2bf(row[72 + lane]);
    if (lane == 63) {
        #pragma unroll
        for (int k = KTOT; k < KPAD; ++k) xbf[(size_t)b * KPAD + k] = 0;
    }
    __syncthreads();

    if (lane == 0) {
        #pragma unroll
        for (int i = 0; i < 9; ++i) P.Rg[sub][0][i] = P.Rs[sub][0][i];
        #pragma unroll
        for (int c3 = 0; c3 < 3; ++c3) P.tg[sub][0][c3] = P.Jl[sub][0][c3];
        for (int i = 1; i < 24; ++i) {
            const int p = parents[i];
            float tmp[9];
            #pragma unroll
            for (int r = 0; r < 3; ++r)
                #pragma unroll
                for (int cc = 0; cc < 3; ++cc)
                    tmp[r * 3 + cc] = P.Rg[sub][p][r * 3 + 0] * P.Rs[sub][i][0 + cc] +
                                      P.Rg[sub][p][r * 3 + 1] * P.Rs[sub][i][3 + cc] +
                                      P.Rg[sub][p][r * 3 + 2] * P.Rs[sub][i][6 + cc];
            #pragma unroll
            for (int q = 0; q < 9; ++q) P.Rg[sub][i][q] = tmp[q];
            const float tr0 = P.Jl[sub][i][0] - P.Jl[sub][p][0];
            const float tr1 = P.Jl[sub][i][1] - P.Jl[sub][p][1];
            const float tr2 = P.Jl[sub][i][2] - P.Jl[sub][p][2];
            #pragma unroll
            for (int r = 0; r < 3; ++r)
                P.tg[sub][i][r] = P.Rg[sub][p][r * 3 + 0] * tr0 + P.Rg[sub][p][r * 3 + 1] * tr1 +
                                  P.Rg[sub][p][r * 3 + 2] * tr2 + P.tg[sub][p][r];
        }
    }
    __syncthreads();

    if (lane < 24) {
        const int j = lane;
        #pragma unroll
        for (int r = 0; r < 3; ++r) {
            const float tt = P.tg[sub][j][r] - (P.Rg[sub][j][r * 3 + 0] * P.Jl[sub][j][0] +
                                                P.Rg[sub][j][r * 3 + 1] * P.Jl[sub][j][1] +
                                                P.Rg[sub][j][r * 3 + 2] * P.Jl[sub][j][2]);
            P.As[sub][j][r * 4 + 0] = P.Rg[sub][j][r * 3 + 0];
            P.As[sub][j][r * 4 + 1] = P.Rg[sub][j][r * 3 + 1];
            P.As[sub][j][r * 4 + 2] = P.Rg[sub][j][r * 3 + 2];
            P.As[sub][j][r * 4 + 3] = tt;
        }
    }
    __syncthreads();

    if (lane < 32) {
        const int r = lane >> 1;     // pq row 0..15
        const int half = lane & 1;   // k half
        unsigned short hi[16], lo[16];
        #pragma unroll
        for (int i = 0; i < 16; ++i) {
            const int j = half * 16 + i;
            float v = 0.f;
            if (r < 12 && j < 24) v = P.As[sub][j][r];
            const unsigned short h = f2bf(v);
            hi[i] = h;
            lo[i] = f2bf(v - bf2f(h));
        }
        unsigned short* dh = ahi + ((size_t)b * 16 + r) * 32 + half * 16;
        unsigned short* dl = alo + ((size_t)b * 16 + r) * 32 + half * 16;
        #pragma unroll
        for (int i = 0; i < 2; ++i) {
            *(float4*)(dh + i * 8) = *(const float4*)(&hi[i * 8]);
            *(float4*)(dl + i * 8) = *(const float4*)(&lo[i * 8]);
        }
    }
}

// ================= k_gemm (r7/r9-verified): grid (323, 4) =================
__global__ __launch_bounds__(256) void k_gemm(const float* __restrict__ vt,
                                              float* __restrict__ out,
                                              float* __restrict__ ws) {
    __shared__ __align__(16) unsigned short Xs[64 * 232];
    const unsigned short* dbf = (const unsigned short*)(ws + WS_DBF);
    const unsigned short* xbf = (const unsigned short*)(ws + WS_XBF);
    const int tid  = threadIdx.x;
    const int wave = tid >> 6;
    const int lane = tid & 63;
    const int col  = lane & 15;
    const int quad = lane >> 4;
    const int n0   = blockIdx.x * 64;
    const int nc   = n0 + wave * 16 + col;

    short8 bfrag[7];
    {
        const unsigned short* brow = dbf + (size_t)nc * KPAD + quad * 8;
        #pragma unroll
        for (int kb = 0; kb < 7; ++kb)
            bfrag[kb] = *(const short8*)(brow + kb * 32);
    }
    const float vtl = (nc < NUM_COORDS) ? vt[nc] : 0.f;
    const bool nok = (nc < NUM_COORDS);

    for (int chunk = 0; chunk < 2; ++chunk) {
        const int m0 = blockIdx.y * 128 + chunk * 64;
        __syncthreads();
        #pragma unroll
        for (int i = 0; i < 7; ++i) {
            const int c = tid + i * 256;
            const int r = c / 28;
            const int off = c % 28;
            const float4 v = *(const float4*)(xbf + (size_t)(m0 + r) * KPAD + off * 8);
            *(float4*)(&Xs[r * 232 + off * 8]) = v;
        }
        __syncthreads();

        #pragma unroll
        for (int mt = 0; mt < 4; ++mt) {
            const unsigned short* arow = &Xs[(mt * 16 + col) * 232 + quad * 8];
            f32x4 acc = {0.f, 0.f, 0.f, 0.f};
            #pragma unroll
            for (int kb = 0; kb < 7; ++kb) {
                const short8 afrag = *(const short8*)(arow + kb * 32);
                acc = __builtin_amdgcn_mfma_f32_16x16x32_bf16(afrag, bfrag[kb], acc, 0, 0, 0);
            }
            if (nok) {
                float* base = out + (size_t)(m0 + mt * 16 + quad * 4) * NUM_COORDS + nc;
                base[0]                       = acc[0] + vtl;
                base[(size_t)NUM_COORDS]      = acc[1] + vtl;
                base[(size_t)2 * NUM_COORDS]  = acc[2] + vtl;
                base[(size_t)3 * NUM_COORDS]  = acc[3] + vtl;
            }
        }
    }
}

// ================= k_skin (r7/r9-verified): grid (108, 16) =================
__global__ __launch_bounds__(256) void k_skin(float* __restrict__ out,
                                              float* __restrict__ ws) {
    __shared__ float Ts[4][64 * 17];
    const unsigned short* whbf = (const unsigned short*)(ws + WS_WHBF);
    const unsigned short* ahi  = (const unsigned short*)(ws + WS_AH);
    const unsigned short* alo  = (const unsigned short*)(ws + WS_AL);
    const int tid  = threadIdx.x;
    const int wave = tid >> 6;
    const int lane = tid & 63;
    const int col  = lane & 15;
    const int quad = lane >> 4;
    const int v0   = blockIdx.x * 64;
    const int b0   = blockIdx.y * 32;

    short8 wfrag[4];
    #pragma unroll
    for (int mt = 0; mt < 4; ++mt)
        wfrag[mt] = *(const short8*)(whbf + (size_t)(v0 + mt * 16 + col) * 32 + quad * 8);

    float* ts = &Ts[wave][0];
    const int vv = v0 + lane;
    const bool vok = (vv < NUM_VERTS);

    for (int nt = wave; nt < 32; nt += 4) {
        const int b = b0 + nt;
        float* orow = out + (size_t)b * NUM_COORDS + (size_t)vv * 3;
        float h0 = 0.f, h1 = 0.f, h2 = 0.f;
        if (vok) { h0 = orow[0]; h1 = orow[1]; h2 = orow[2]; }

        const short8 bh = *(const short8*)(ahi + ((size_t)b * 16 + col) * 32 + quad * 8);
        const short8 bl = *(const short8*)(alo + ((size_t)b * 16 + col) * 32 + quad * 8);

        f32x4 acc[4];
        #pragma unroll
        for (int mt = 0; mt < 4; ++mt) {
            f32x4 z = {0.f, 0.f, 0.f, 0.f};
            z = __builtin_amdgcn_mfma_f32_16x16x32_bf16(wfrag[mt], bh, z, 0, 0, 0);
            z = __builtin_amdgcn_mfma_f32_16x16x32_bf16(wfrag[mt], bl, z, 0, 0, 0);
            acc[mt] = z;
        }
        #pragma unroll
        for (int mt = 0; mt < 4; ++mt)
            #pragma unroll
            for (int r = 0; r < 4; ++r)
                ts[(mt * 16 + quad * 4 + r) * 17 + col] = acc[mt][r];

        float Tp[12];
        #pragma unroll
        for (int i = 0; i < 12; ++i) Tp[i] = ts[lane * 17 + i];

        if (vok) {
            const float o0 = Tp[0] * h0 + Tp[1] * h1 + Tp[2]  * h2 + Tp[3];
            const float o1 = Tp[4] * h0 + Tp[5] * h1 + Tp[6]  * h2 + Tp[7];
            const float o2 = Tp[8] * h0 + Tp[9] * h1 + Tp[10] * h2 + Tp[11];
            orow[0] = o0; orow[1] = o1; orow[2] = o2;
        }
    }
}

extern "C" void kernel_launch(void* const* d_in, const int* in_sizes, int n_in,
                              void* d_out, int out_size, void* d_ws, size_t ws_size,
                              hipStream_t stream) {
    const float* x  = (const float*)d_in[0];
    const float* vt = (const float*)d_in[1];
    const float* sd = (const float*)d_in[2];
    const float* Jr = (const float*)d_in[3];
    const float* pd = (const float*)d_in[4];
    const float* w  = (const float*)d_in[5];
    const int* parents = (const int*)d_in[6];
    float* out = (float*)d_out;
    float* ws  = (float*)d_ws;

    k_prep<<<459, 256, 0, stream>>>(Jr, sd, pd, vt, w, ws);
    k_pb  <<<128, 256, 0, stream>>>(x, parents, ws);
    k_gemm<<<dim3(323, 4), 256, 0, stream>>>(vt, out, ws);
    k_skin<<<dim3(108, 16), 256, 0, stream>>>(out, ws);
}

// Round 12
// 161.130 us; speedup vs baseline: 1.8008x; 1.0130x over previous
//
#include <hip/hip_runtime.h>

#define NUM_JOINTS 24
#define NUM_VERTS  6890
#define NUM_COORDS (NUM_VERTS * 3)   // 20670
#define NUM_BETAS  10
#define KTOT       217               // 10 betas + 207 pose features
#define KPAD       224               // padded K for MFMA (7 x 32)
#define BATCH      512
#define VPAD       6912              // padded vertex count

// ---- ws layout (float offsets); ushort regions: floats = ushorts/2 ----
#define WS_SJP  0          //  85536: float 108 strips x 792 partials (s*24+j, s=src 0..32)
#define WS_XBF  85536      //  57344: ushort 512 x 224
#define WS_DBF  142880     // 2322432: ushort 20736 x 224
#define WS_WHBF 2465312    // 110592: ushort 6912 x 32
#define WS_AH   2575904    // 131072: ushort 8192 x 32
#define WS_AL   2706976    // 131072: ushort 8192 x 32  -> total 2838048 floats ~11.4 MB

typedef __attribute__((ext_vector_type(8))) short short8;
typedef __attribute__((ext_vector_type(4))) float f32x4;

__device__ inline unsigned short f2bf(float f) {
    union { float f; unsigned u; } c; c.f = f;
    unsigned u = c.u;
    u += 0x7fffu + ((u >> 16) & 1u);   // RNE
    return (unsigned short)(u >> 16);
}
__device__ inline float bf2f(unsigned short h) {
    union { unsigned u; float f; } c; c.u = ((unsigned)h) << 16;
    return c.f;
}

struct PBShm {
    float Rs[4][24][9];
    float Jl[4][24][3];
    float Rg[4][24][9];
    float tg[4][24][3];
    float As[4][24][12];
};   // 13824 B

// ================= k_prep (r10-verified): 459 blocks =================
__global__ __launch_bounds__(256) void k_prep(const float* __restrict__ Jr,
                                              const float* __restrict__ sd,
                                              const float* __restrict__ pd,
                                              const float* __restrict__ vt,
                                              const float* __restrict__ w,
                                              float* __restrict__ ws) {
    __shared__ __align__(16) unsigned char smem[28928];
    const int t   = blockIdx.x;
    const int tid = threadIdx.x;
    unsigned short* whbf = (unsigned short*)(ws + WS_WHBF);
    unsigned short* dbf  = (unsigned short*)(ws + WS_DBF);

    if (t < 27) {
        const int v = t * 256 + tid;      // < 6912
        const bool ok = (v < NUM_VERTS);
        unsigned short row[32];
        #pragma unroll
        for (int j = 0; j < 32; ++j)
            row[j] = f2bf((ok && j < 24) ? w[v * 24 + j] : 0.f);
        #pragma unroll
        for (int i = 0; i < 4; ++i)
            *(float4*)(whbf + (size_t)v * 32 + i * 8) = *(const float4*)(&row[i * 8]);
    } else if (t < 351) {
        unsigned* L = (unsigned*)smem;        // [64][113] dwords
        const int c0   = (t - 27) * 64;
        const int lane = tid & 63;
        const int grp  = tid >> 6;
        const int c    = c0 + lane;
        const bool cv  = (c < NUM_COORDS);
        #pragma unroll 4
        for (int i = 0; i < 28; ++i) {
            const int p  = i * 4 + grp;
            const int k0 = 2 * p, k1 = k0 + 1;
            float v0 = 0.f, v1 = 0.f;
            if (cv) {
                v0 = (k0 < 10) ? sd[(size_t)k0 * NUM_COORDS + c]
                   : (k0 < KTOT) ? pd[(size_t)(k0 - 10) * NUM_COORDS + c] : 0.f;
                v1 = (k1 < 10) ? sd[(size_t)k1 * NUM_COORDS + c]
                   : (k1 < KTOT) ? pd[(size_t)(k1 - 10) * NUM_COORDS + c] : 0.f;
            }
            L[lane * 113 + p] = (unsigned)f2bf(v0) | ((unsigned)f2bf(v1) << 16);
        }
        __syncthreads();
        #pragma unroll
        for (int i = 0; i < 7; ++i) {
            const int idx = i * 256 + tid;
            const int row = idx / 28;
            const int q   = idx % 28;
            uint4 val;
            val.x = L[row * 113 + q * 4 + 0];
            val.y = L[row * 113 + q * 4 + 1];
            val.z = L[row * 113 + q * 4 + 2];
            val.w = L[row * 113 + q * 4 + 3];
            *(uint4*)(dbf + (size_t)(c0 + row) * KPAD + q * 8) = val;
        }
    } else {
        float* Jl = (float*)smem;
        float* S  = (float*)smem + 64 * 25;
        const int strip = t - 351;
        const int v0 = strip * 64;
        #pragma unroll
        for (int i = 0; i < 6; ++i) {
            const int idx = i * 256 + tid;
            const int v = idx / 24, j = idx % 24;
            Jl[v * 25 + j] = (v0 + v < NUM_VERTS) ? Jr[(size_t)(v0 + v) * 24 + j] : 0.f;
        }
        #pragma unroll
        for (int i = 0; i < 9; ++i) {
            const int idx = i * 256 + tid;
            if (idx < 33 * 64) {
                const int s = idx / 64, v = idx % 64;
                float val = 0.f;
                if (v0 + v < NUM_VERTS) {
                    if (s < 30) val = sd[(size_t)(s / 3) * NUM_COORDS + (size_t)(v0 + v) * 3 + (s % 3)];
                    else        val = vt[(size_t)(v0 + v) * 3 + (s - 30)];
                }
                S[s * 64 + v] = val;
            }
        }
        __syncthreads();
        float* wsp = ws + WS_SJP + (size_t)strip * 792;
        for (int o = tid; o < 792; o += 256) {
            const int s = o / 24, j = o % 24;
            float sum = 0.f;
            #pragma unroll 8
            for (int v = 0; v < 64; ++v)
                sum += S[s * 64 + v] * Jl[v * 25 + j];
            wsp[o] = sum;
        }
    }
}

// ================= k_pb (r10-verified): 128 blocks x 4 batches =================
__global__ __launch_bounds__(256) void k_pb(const float* __restrict__ x,
                                            const int* __restrict__ parents,
                                            float* __restrict__ ws) {
    __shared__ PBShm P;
    __shared__ float SJf[792];
    unsigned short* xbf = (unsigned short*)(ws + WS_XBF);
    unsigned short* ahi = (unsigned short*)(ws + WS_AH);
    unsigned short* alo = (unsigned short*)(ws + WS_AL);
    const int tid = threadIdx.x;

    {
        const float* wsp = ws + WS_SJP;
        for (int o = tid; o < 792; o += 256) {
            float sum = 0.f;
            for (int s2 = 0; s2 < 108; ++s2)
                sum += wsp[(size_t)s2 * 792 + o];
            SJf[o] = sum;
        }
    }
    __syncthreads();

    const int sub  = tid >> 6;
    const int lane = tid & 63;
    const int b = blockIdx.x * 4 + sub;
    const float* row = x + b * (NUM_BETAS + 72);

    if (lane < 24) {
        const int j = lane;
        const float t0 = row[3 * j + 0], t1 = row[3 * j + 1], t2 = row[3 * j + 2];
        const float a0 = t0 + 1e-8f, a1 = t1 + 1e-8f, a2 = t2 + 1e-8f;
        const float angle = sqrtf(a0 * a0 + a1 * a1 + a2 * a2);
        const float inv = 1.0f / angle;
        const float rx = t0 * inv, ry = t1 * inv, rz = t2 * inv;
        const float c = cosf(angle), sn = sinf(angle), o = 1.f - c;
        float R[9];
        R[0] = c + o * rx * rx;       R[1] = o * rx * ry - sn * rz; R[2] = o * rx * rz + sn * ry;
        R[3] = o * rx * ry + sn * rz; R[4] = c + o * ry * ry;       R[5] = o * ry * rz - sn * rx;
        R[6] = o * rx * rz - sn * ry; R[7] = o * ry * rz + sn * rx; R[8] = c + o * rz * rz;
        #pragma unroll
        for (int i = 0; i < 9; ++i) P.Rs[sub][j][i] = R[i];
        #pragma unroll
        for (int c3 = 0; c3 < 3; ++c3) {
            float s = SJf[(30 + c3) * 24 + j];
            #pragma unroll
            for (int k = 0; k < NUM_BETAS; ++k)
                s += row[72 + k] * SJf[(k * 3 + c3) * 24 + j];
            P.Jl[sub][j][c3] = s;
        }
        if (j >= 1) {
            #pragma unroll
            for (int i = 0; i < 9; ++i) {
                const float pf = R[i] - ((i == 0 || i == 4 || i == 8) ? 1.f : 0.f);
                xbf[(size_t)b * KPAD + 10 + (j - 1) * 9 + i] = f2bf(pf);
            }
        }
    }
    if (lane < NUM_BETAS) xbf[(size_t)b * KPAD + lane] = f2bf(row[72 + lane]);
    if (lane == 63) {
        #pragma unroll
        for (int k = KTOT; k < KPAD; ++k) xbf[(size_t)b * KPAD + k] = 0;
    }
    __syncthreads();

    if (lane == 0) {
        #pragma unroll
        for (int i = 0; i < 9; ++i) P.Rg[sub][0][i] = P.Rs[sub][0][i];
        #pragma unroll
        for (int c3 = 0; c3 < 3; ++c3) P.tg[sub][0][c3] = P.Jl[sub][0][c3];
        for (int i = 1; i < 24; ++i) {
            const int p = parents[i];
            float tmp[9];
            #pragma unroll
            for (int r = 0; r < 3; ++r)
                #pragma unroll
                for (int cc = 0; cc < 3; ++cc)
                    tmp[r * 3 + cc] = P.Rg[sub][p][r * 3 + 0] * P.Rs[sub][i][0 + cc] +
                                      P.Rg[sub][p][r * 3 + 1] * P.Rs[sub][i][3 + cc] +
                                      P.Rg[sub][p][r * 3 + 2] * P.Rs[sub][i][6 + cc];
            #pragma unroll
            for (int q = 0; q < 9; ++q) P.Rg[sub][i][q] = tmp[q];
            const float tr0 = P.Jl[sub][i][0] - P.Jl[sub][p][0];
            const float tr1 = P.Jl[sub][i][1] - P.Jl[sub][p][1];
            const float tr2 = P.Jl[sub][i][2] - P.Jl[sub][p][2];
            #pragma unroll
            for (int r = 0; r < 3; ++r)
                P.tg[sub][i][r] = P.Rg[sub][p][r * 3 + 0] * tr0 + P.Rg[sub][p][r * 3 + 1] * tr1 +
                                  P.Rg[sub][p][r * 3 + 2] * tr2 + P.tg[sub][p][r];
        }
    }
    __syncthreads();

    if (lane < 24) {
        const int j = lane;
        #pragma unroll
        for (int r = 0; r < 3; ++r) {
            const float tt = P.tg[sub][j][r] - (P.Rg[sub][j][r * 3 + 0] * P.Jl[sub][j][0] +
                                                P.Rg[sub][j][r * 3 + 1] * P.Jl[sub][j][1] +
                                                P.Rg[sub][j][r * 3 + 2] * P.Jl[sub][j][2]);
            P.As[sub][j][r * 4 + 0] = P.Rg[sub][j][r * 3 + 0];
            P.As[sub][j][r * 4 + 1] = P.Rg[sub][j][r * 3 + 1];
            P.As[sub][j][r * 4 + 2] = P.Rg[sub][j][r * 3 + 2];
            P.As[sub][j][r * 4 + 3] = tt;
        }
    }
    __syncthreads();

    if (lane < 32) {
        const int r = lane >> 1;
        const int half = lane & 1;
        unsigned short hi[16], lo[16];
        #pragma unroll
        for (int i = 0; i < 16; ++i) {
            const int j = half * 16 + i;
            float v = 0.f;
            if (r < 12 && j < 24) v = P.As[sub][j][r];
            const unsigned short h = f2bf(v);
            hi[i] = h;
            lo[i] = f2bf(v - bf2f(h));
        }
        unsigned short* dh = ahi + ((size_t)b * 16 + r) * 32 + half * 16;
        unsigned short* dl = alo + ((size_t)b * 16 + r) * 32 + half * 16;
        #pragma unroll
        for (int i = 0; i < 2; ++i) {
            *(float4*)(dh + i * 8) = *(const float4*)(&hi[i * 8]);
            *(float4*)(dl + i * 8) = *(const float4*)(&lo[i * 8]);
        }
    }
}

// ================= k_gemmA: fused Phase A extracted standalone (BISECT) =================
// grid (108, 8): block = 192 coords (64 verts) x 64 batches (2 chunks of 32).
// Per wave: 3 persistent B-frag n-tiles (48 coords), 2 m-tiles per chunk.
__global__ __launch_bounds__(256) void k_gemmA(const float* __restrict__ vt,
                                               float* __restrict__ out,
                                               float* __restrict__ ws) {
    __shared__ __align__(16) unsigned short Xs[32 * 232];
    const unsigned short* dbf = (const unsigned short*)(ws + WS_DBF);
    const unsigned short* xbf = (const unsigned short*)(ws + WS_XBF);
    const int tid  = threadIdx.x;
    const int wave = tid >> 6;
    const int lane = tid & 63;
    const int col  = lane & 15;
    const int quad = lane >> 4;
    const int c0   = blockIdx.x * 192;

    short8 bfrag[3][7];
    float vtl[3];
    #pragma unroll
    for (int nt = 0; nt < 3; ++nt) {
        const int nc = c0 + wave * 48 + nt * 16 + col;
        const unsigned short* brow = dbf + (size_t)nc * KPAD + quad * 8;
        #pragma unroll
        for (int kb = 0; kb < 7; ++kb)
            bfrag[nt][kb] = *(const short8*)(brow + kb * 32);
        vtl[nt] = (nc < NUM_COORDS) ? vt[nc] : 0.f;
    }

    for (int chunk = 0; chunk < 2; ++chunk) {
        const int m0 = blockIdx.y * 64 + chunk * 32;
        __syncthreads();
        #pragma unroll
        for (int i = 0; i < 4; ++i) {
            const int c = tid + i * 256;
            if (c < 32 * 28) {
                const int r = c / 28, off = c % 28;
                *(float4*)(&Xs[r * 232 + off * 8]) =
                    *(const float4*)(xbf + (size_t)(m0 + r) * KPAD + off * 8);
            }
        }
        __syncthreads();

        #pragma unroll
        for (int mt = 0; mt < 2; ++mt) {
            const unsigned short* arow = &Xs[(mt * 16 + col) * 232 + quad * 8];
            f32x4 acc[3] = {{0.f,0.f,0.f,0.f},{0.f,0.f,0.f,0.f},{0.f,0.f,0.f,0.f}};
            #pragma unroll
            for (int kb = 0; kb < 7; ++kb) {
                const short8 af = *(const short8*)(arow + kb * 32);
                #pragma unroll
                for (int nt = 0; nt < 3; ++nt)
                    acc[nt] = __builtin_amdgcn_mfma_f32_16x16x32_bf16(af, bfrag[nt][kb], acc[nt], 0, 0, 0);
            }
            #pragma unroll
            for (int nt = 0; nt < 3; ++nt) {
                const int nc = c0 + wave * 48 + nt * 16 + col;
                if (nc < NUM_COORDS) {
                    float* base = out + (size_t)(m0 + mt * 16 + quad * 4) * NUM_COORDS + nc;
                    base[0]                      = acc[nt][0] + vtl[nt];
                    base[(size_t)NUM_COORDS]     = acc[nt][1] + vtl[nt];
                    base[(size_t)2 * NUM_COORDS] = acc[nt][2] + vtl[nt];
                    base[(size_t)3 * NUM_COORDS] = acc[nt][3] + vtl[nt];
                }
            }
        }
    }
}

// ================= k_skin (r10-verified): grid (108, 16) =================
__global__ __launch_bounds__(256) void k_skin(float* __restrict__ out,
                                              float* __restrict__ ws) {
    __shared__ float Ts[4][64 * 17];
    const unsigned short* whbf = (const unsigned short*)(ws + WS_WHBF);
    const unsigned short* ahi  = (const unsigned short*)(ws + WS_AH);
    const unsigned short* alo  = (const unsigned short*)(ws + WS_AL);
    const int tid  = threadIdx.x;
    const int wave = tid >> 6;
    const int lane = tid & 63;
    const int col  = lane & 15;
    const int quad = lane >> 4;
    const int v0   = blockIdx.x * 64;
    const int b0   = blockIdx.y * 32;

    short8 wfrag[4];
    #pragma unroll
    for (int mt = 0; mt < 4; ++mt)
        wfrag[mt] = *(const short8*)(whbf + (size_t)(v0 + mt * 16 + col) * 32 + quad * 8);

    float* ts = &Ts[wave][0];
    const int vv = v0 + lane;
    const bool vok = (vv < NUM_VERTS);

    for (int nt = wave; nt < 32; nt += 4) {
        const int b = b0 + nt;
        float* orow = out + (size_t)b * NUM_COORDS + (size_t)vv * 3;
        float h0 = 0.f, h1 = 0.f, h2 = 0.f;
        if (vok) { h0 = orow[0]; h1 = orow[1]; h2 = orow[2]; }

        const short8 bh = *(const short8*)(ahi + ((size_t)b * 16 + col) * 32 + quad * 8);
        const short8 bl = *(const short8*)(alo + ((size_t)b * 16 + col) * 32 + quad * 8);

        f32x4 acc[4];
        #pragma unroll
        for (int mt = 0; mt < 4; ++mt) {
            f32x4 z = {0.f, 0.f, 0.f, 0.f};
            z = __builtin_amdgcn_mfma_f32_16x16x32_bf16(wfrag[mt], bh, z, 0, 0, 0);
            z = __builtin_amdgcn_mfma_f32_16x16x32_bf16(wfrag[mt], bl, z, 0, 0, 0);
            acc[mt] = z;
        }
        #pragma unroll
        for (int mt = 0; mt < 4; ++mt)
            #pragma unroll
            for (int r = 0; r < 4; ++r)
                ts[(mt * 16 + quad * 4 + r) * 17 + col] = acc[mt][r];

        float Tp[12];
        #pragma unroll
        for (int i = 0; i < 12; ++i) Tp[i] = ts[lane * 17 + i];

        if (vok) {
            const float o0 = Tp[0] * h0 + Tp[1] * h1 + Tp[2]  * h2 + Tp[3];
            const float o1 = Tp[4] * h0 + Tp[5] * h1 + Tp[6]  * h2 + Tp[7];
            const float o2 = Tp[8] * h0 + Tp[9] * h1 + Tp[10] * h2 + Tp[11];
            orow[0] = o0; orow[1] = o1; orow[2] = o2;
        }
    }
}

extern "C" void kernel_launch(void* const* d_in, const int* in_sizes, int n_in,
                              void* d_out, int out_size, void* d_ws, size_t ws_size,
                              hipStream_t stream) {
    const float* x  = (const float*)d_in[0];
    const float* vt = (const float*)d_in[1];
    const float* sd = (const float*)d_in[2];
    const float* Jr = (const float*)d_in[3];
    const float* pd = (const float*)d_in[4];
    const float* w  = (const float*)d_in[5];
    const int* parents = (const int*)d_in[6];
    float* out = (float*)d_out;
    float* ws  = (float*)d_ws;

    k_prep <<<459, 256, 0, stream>>>(Jr, sd, pd, vt, w, ws);
    k_pb   <<<128, 256, 0, stream>>>(x, parents, ws);
    k_gemmA<<<dim3(108, 8), 256, 0, stream>>>(vt, out, ws);
    k_skin <<<dim3(108, 16), 256, 0, stream>>>(out, ws);
}

// Round 13
// 160.586 us; speedup vs baseline: 1.8069x; 1.0034x over previous
//
#include <hip/hip_runtime.h>

#define NUM_JOINTS 24
#define NUM_VERTS  6890
#define NUM_COORDS (NUM_VERTS * 3)   // 20670
#define NUM_BETAS  10
#define KTOT       217               // 10 betas + 207 pose features
#define KPAD       224               // padded K for MFMA (7 x 32)
#define BATCH      512
#define VPAD       6912              // padded vertex count

// ---- ws layout (float offsets); ushort regions: floats = ushorts/2 ----
#define WS_SJP  0          //  85536: float 108 strips x 792 partials (s*24+j, s=src 0..32)
#define WS_XBF  85536      //  57344: ushort 512 x 224
#define WS_DBF  142880     // 2322432: ushort 20736 x 224
#define WS_WHBF 2465312    // 110592: ushort 6912 x 32
#define WS_AH   2575904    // 131072: ushort 8192 x 32
#define WS_AL   2706976    // 131072: ushort 8192 x 32  -> total 2838048 floats ~11.4 MB

typedef __attribute__((ext_vector_type(8))) short short8;
typedef __attribute__((ext_vector_type(4))) float f32x4;

__device__ inline unsigned short f2bf(float f) {
    union { float f; unsigned u; } c; c.f = f;
    unsigned u = c.u;
    u += 0x7fffu + ((u >> 16) & 1u);   // RNE
    return (unsigned short)(u >> 16);
}
__device__ inline float bf2f(unsigned short h) {
    union { unsigned u; float f; } c; c.u = ((unsigned)h) << 16;
    return c.f;
}

struct PBShm {
    float Rs[4][24][9];
    float Jl[4][24][3];
    float Rg[4][24][9];
    float tg[4][24][3];
    float As[4][24][12];
};   // 13824 B

// ================= k_prep (r10-verified): 459 blocks =================
__global__ __launch_bounds__(256) void k_prep(const float* __restrict__ Jr,
                                              const float* __restrict__ sd,
                                              const float* __restrict__ pd,
                                              const float* __restrict__ vt,
                                              const float* __restrict__ w,
                                              float* __restrict__ ws) {
    __shared__ __align__(16) unsigned char smem[28928];
    const int t   = blockIdx.x;
    const int tid = threadIdx.x;
    unsigned short* whbf = (unsigned short*)(ws + WS_WHBF);
    unsigned short* dbf  = (unsigned short*)(ws + WS_DBF);

    if (t < 27) {
        const int v = t * 256 + tid;      // < 6912
        const bool ok = (v < NUM_VERTS);
        unsigned short row[32];
        #pragma unroll
        for (int j = 0; j < 32; ++j)
            row[j] = f2bf((ok && j < 24) ? w[v * 24 + j] : 0.f);
        #pragma unroll
        for (int i = 0; i < 4; ++i)
            *(float4*)(whbf + (size_t)v * 32 + i * 8) = *(const float4*)(&row[i * 8]);
    } else if (t < 351) {
        unsigned* L = (unsigned*)smem;        // [64][113] dwords
        const int c0   = (t - 27) * 64;
        const int lane = tid & 63;
        const int grp  = tid >> 6;
        const int c    = c0 + lane;
        const bool cv  = (c < NUM_COORDS);
        #pragma unroll 4
        for (int i = 0; i < 28; ++i) {
            const int p  = i * 4 + grp;
            const int k0 = 2 * p, k1 = k0 + 1;
            float v0 = 0.f, v1 = 0.f;
            if (cv) {
                v0 = (k0 < 10) ? sd[(size_t)k0 * NUM_COORDS + c]
                   : (k0 < KTOT) ? pd[(size_t)(k0 - 10) * NUM_COORDS + c] : 0.f;
                v1 = (k1 < 10) ? sd[(size_t)k1 * NUM_COORDS + c]
                   : (k1 < KTOT) ? pd[(size_t)(k1 - 10) * NUM_COORDS + c] : 0.f;
            }
            L[lane * 113 + p] = (unsigned)f2bf(v0) | ((unsigned)f2bf(v1) << 16);
        }
        __syncthreads();
        #pragma unroll
        for (int i = 0; i < 7; ++i) {
            const int idx = i * 256 + tid;
            const int row = idx / 28;
            const int q   = idx % 28;
            uint4 val;
            val.x = L[row * 113 + q * 4 + 0];
            val.y = L[row * 113 + q * 4 + 1];
            val.z = L[row * 113 + q * 4 + 2];
            val.w = L[row * 113 + q * 4 + 3];
            *(uint4*)(dbf + (size_t)(c0 + row) * KPAD + q * 8) = val;
        }
    } else {
        float* Jl = (float*)smem;
        float* S  = (float*)smem + 64 * 25;
        const int strip = t - 351;
        const int v0 = strip * 64;
        #pragma unroll
        for (int i = 0; i < 6; ++i) {
            const int idx = i * 256 + tid;
            const int v = idx / 24, j = idx % 24;
            Jl[v * 25 + j] = (v0 + v < NUM_VERTS) ? Jr[(size_t)(v0 + v) * 24 + j] : 0.f;
        }
        #pragma unroll
        for (int i = 0; i < 9; ++i) {
            const int idx = i * 256 + tid;
            if (idx < 33 * 64) {
                const int s = idx / 64, v = idx % 64;
                float val = 0.f;
                if (v0 + v < NUM_VERTS) {
                    if (s < 30) val = sd[(size_t)(s / 3) * NUM_COORDS + (size_t)(v0 + v) * 3 + (s % 3)];
                    else        val = vt[(size_t)(v0 + v) * 3 + (s - 30)];
                }
                S[s * 64 + v] = val;
            }
        }
        __syncthreads();
        float* wsp = ws + WS_SJP + (size_t)strip * 792;
        for (int o = tid; o < 792; o += 256) {
            const int s = o / 24, j = o % 24;
            float sum = 0.f;
            #pragma unroll 8
            for (int v = 0; v < 64; ++v)
                sum += S[s * 64 + v] * Jl[v * 25 + j];
            wsp[o] = sum;
        }
    }
}

// ================= k_pb (r10-verified): 128 blocks x 4 batches =================
__global__ __launch_bounds__(256) void k_pb(const float* __restrict__ x,
                                            const int* __restrict__ parents,
                                            float* __restrict__ ws) {
    __shared__ PBShm P;
    __shared__ float SJf[792];
    unsigned short* xbf = (unsigned short*)(ws + WS_XBF);
    unsigned short* ahi = (unsigned short*)(ws + WS_AH);
    unsigned short* alo = (unsigned short*)(ws + WS_AL);
    const int tid = threadIdx.x;

    {
        const float* wsp = ws + WS_SJP;
        for (int o = tid; o < 792; o += 256) {
            float sum = 0.f;
            for (int s2 = 0; s2 < 108; ++s2)
                sum += wsp[(size_t)s2 * 792 + o];
            SJf[o] = sum;
        }
    }
    __syncthreads();

    const int sub  = tid >> 6;
    const int lane = tid & 63;
    const int b = blockIdx.x * 4 + sub;
    const float* row = x + b * (NUM_BETAS + 72);

    if (lane < 24) {
        const int j = lane;
        const float t0 = row[3 * j + 0], t1 = row[3 * j + 1], t2 = row[3 * j + 2];
        const float a0 = t0 + 1e-8f, a1 = t1 + 1e-8f, a2 = t2 + 1e-8f;
        const float angle = sqrtf(a0 * a0 + a1 * a1 + a2 * a2);
        const float inv = 1.0f / angle;
        const float rx = t0 * inv, ry = t1 * inv, rz = t2 * inv;
        const float c = cosf(angle), sn = sinf(angle), o = 1.f - c;
        float R[9];
        R[0] = c + o * rx * rx;       R[1] = o * rx * ry - sn * rz; R[2] = o * rx * rz + sn * ry;
        R[3] = o * rx * ry + sn * rz; R[4] = c + o * ry * ry;       R[5] = o * ry * rz - sn * rx;
        R[6] = o * rx * rz - sn * ry; R[7] = o * ry * rz + sn * rx; R[8] = c + o * rz * rz;
        #pragma unroll
        for (int i = 0; i < 9; ++i) P.Rs[sub][j][i] = R[i];
        #pragma unroll
        for (int c3 = 0; c3 < 3; ++c3) {
            float s = SJf[(30 + c3) * 24 + j];
            #pragma unroll
            for (int k = 0; k < NUM_BETAS; ++k)
                s += row[72 + k] * SJf[(k * 3 + c3) * 24 + j];
            P.Jl[sub][j][c3] = s;
        }
        if (j >= 1) {
            #pragma unroll
            for (int i = 0; i < 9; ++i) {
                const float pf = R[i] - ((i == 0 || i == 4 || i == 8) ? 1.f : 0.f);
                xbf[(size_t)b * KPAD + 10 + (j - 1) * 9 + i] = f2bf(pf);
            }
        }
    }
    if (lane < NUM_BETAS) xbf[(size_t)b * KPAD + lane] = f2bf(row[72 + lane]);
    if (lane == 63) {
        #pragma unroll
        for (int k = KTOT; k < KPAD; ++k) xbf[(size_t)b * KPAD + k] = 0;
    }
    __syncthreads();

    if (lane == 0) {
        #pragma unroll
        for (int i = 0; i < 9; ++i) P.Rg[sub][0][i] = P.Rs[sub][0][i];
        #pragma unroll
        for (int c3 = 0; c3 < 3; ++c3) P.tg[sub][0][c3] = P.Jl[sub][0][c3];
        for (int i = 1; i < 24; ++i) {
            const int p = parents[i];
            float tmp[9];
            #pragma unroll
            for (int r = 0; r < 3; ++r)
                #pragma unroll
                for (int cc = 0; cc < 3; ++cc)
                    tmp[r * 3 + cc] = P.Rg[sub][p][r * 3 + 0] * P.Rs[sub][i][0 + cc] +
                                      P.Rg[sub][p][r * 3 + 1] * P.Rs[sub][i][3 + cc] +
                                      P.Rg[sub][p][r * 3 + 2] * P.Rs[sub][i][6 + cc];
            #pragma unroll
            for (int q = 0; q < 9; ++q) P.Rg[sub][i][q] = tmp[q];
            const float tr0 = P.Jl[sub][i][0] - P.Jl[sub][p][0];
            const float tr1 = P.Jl[sub][i][1] - P.Jl[sub][p][1];
            const float tr2 = P.Jl[sub][i][2] - P.Jl[sub][p][2];
            #pragma unroll
            for (int r = 0; r < 3; ++r)
                P.tg[sub][i][r] = P.Rg[sub][p][r * 3 + 0] * tr0 + P.Rg[sub][p][r * 3 + 1] * tr1 +
                                  P.Rg[sub][p][r * 3 + 2] * tr2 + P.tg[sub][p][r];
        }
    }
    __syncthreads();

    if (lane < 24) {
        const int j = lane;
        #pragma unroll
        for (int r = 0; r < 3; ++r) {
            const float tt = P.tg[sub][j][r] - (P.Rg[sub][j][r * 3 + 0] * P.Jl[sub][j][0] +
                                                P.Rg[sub][j][r * 3 + 1] * P.Jl[sub][j][1] +
                                                P.Rg[sub][j][r * 3 + 2] * P.Jl[sub][j][2]);
            P.As[sub][j][r * 4 + 0] = P.Rg[sub][j][r * 3 + 0];
            P.As[sub][j][r * 4 + 1] = P.Rg[sub][j][r * 3 + 1];
            P.As[sub][j][r * 4 + 2] = P.Rg[sub][j][r * 3 + 2];
            P.As[sub][j][r * 4 + 3] = tt;
        }
    }
    __syncthreads();

    if (lane < 32) {
        const int r = lane >> 1;
        const int half = lane & 1;
        unsigned short hi[16], lo[16];
        #pragma unroll
        for (int i = 0; i < 16; ++i) {
            const int j = half * 16 + i;
            float v = 0.f;
            if (r < 12 && j < 24) v = P.As[sub][j][r];
            const unsigned short h = f2bf(v);
            hi[i] = h;
            lo[i] = f2bf(v - bf2f(h));
        }
        unsigned short* dh = ahi + ((size_t)b * 16 + r) * 32 + half * 16;
        unsigned short* dl = alo + ((size_t)b * 16 + r) * 32 + half * 16;
        #pragma unroll
        for (int i = 0; i < 2; ++i) {
            *(float4*)(dh + i * 8) = *(const float4*)(&hi[i * 8]);
            *(float4*)(dl + i * 8) = *(const float4*)(&lo[i * 8]);
        }
    }
}

// ================= k_gemmA (r12-verified body): grid (108, 4), 4 chunks =================
// block = 192 coords (64 verts) x 128 batches (4 chunks of 32); dbf re-read 4x not 8x.
__global__ __launch_bounds__(256) void k_gemmA(const float* __restrict__ vt,
                                               float* __restrict__ out,
                                               float* __restrict__ ws) {
    __shared__ __align__(16) unsigned short Xs[32 * 232];
    const unsigned short* dbf = (const unsigned short*)(ws + WS_DBF);
    const unsigned short* xbf = (const unsigned short*)(ws + WS_XBF);
    const int tid  = threadIdx.x;
    const int wave = tid >> 6;
    const int lane = tid & 63;
    const int col  = lane & 15;
    const int quad = lane >> 4;
    const int c0   = blockIdx.x * 192;

    short8 bfrag[3][7];
    float vtl[3];
    #pragma unroll
    for (int nt = 0; nt < 3; ++nt) {
        const int nc = c0 + wave * 48 + nt * 16 + col;
        const unsigned short* brow = dbf + (size_t)nc * KPAD + quad * 8;
        #pragma unroll
        for (int kb = 0; kb < 7; ++kb)
            bfrag[nt][kb] = *(const short8*)(brow + kb * 32);
        vtl[nt] = (nc < NUM_COORDS) ? vt[nc] : 0.f;
    }

    for (int chunk = 0; chunk < 4; ++chunk) {
        const int m0 = blockIdx.y * 128 + chunk * 32;
        __syncthreads();
        #pragma unroll
        for (int i = 0; i < 4; ++i) {
            const int c = tid + i * 256;
            if (c < 32 * 28) {
                const int r = c / 28, off = c % 28;
                *(float4*)(&Xs[r * 232 + off * 8]) =
                    *(const float4*)(xbf + (size_t)(m0 + r) * KPAD + off * 8);
            }
        }
        __syncthreads();

        #pragma unroll
        for (int mt = 0; mt < 2; ++mt) {
            const unsigned short* arow = &Xs[(mt * 16 + col) * 232 + quad * 8];
            f32x4 acc[3] = {{0.f,0.f,0.f,0.f},{0.f,0.f,0.f,0.f},{0.f,0.f,0.f,0.f}};
            #pragma unroll
            for (int kb = 0; kb < 7; ++kb) {
                const short8 af = *(const short8*)(arow + kb * 32);
                #pragma unroll
                for (int nt = 0; nt < 3; ++nt)
                    acc[nt] = __builtin_amdgcn_mfma_f32_16x16x32_bf16(af, bfrag[nt][kb], acc[nt], 0, 0, 0);
            }
            #pragma unroll
            for (int nt = 0; nt < 3; ++nt) {
                const int nc = c0 + wave * 48 + nt * 16 + col;
                if (nc < NUM_COORDS) {
                    float* base = out + (size_t)(m0 + mt * 16 + quad * 4) * NUM_COORDS + nc;
                    base[0]                      = acc[nt][0] + vtl[nt];
                    base[(size_t)NUM_COORDS]     = acc[nt][1] + vtl[nt];
                    base[(size_t)2 * NUM_COORDS] = acc[nt][2] + vtl[nt];
                    base[(size_t)3 * NUM_COORDS] = acc[nt][3] + vtl[nt];
                }
            }
        }
    }
}

// ================= k_skin: grid (108, 8), 64 batches/block, Ts stride 20, NT stores =================
__global__ __launch_bounds__(256) void k_skin(float* __restrict__ out,
                                              float* __restrict__ ws) {
    __shared__ __align__(16) float Ts[4][64 * 20];
    const unsigned short* whbf = (const unsigned short*)(ws + WS_WHBF);
    const unsigned short* ahi  = (const unsigned short*)(ws + WS_AH);
    const unsigned short* alo  = (const unsigned short*)(ws + WS_AL);
    const int tid  = threadIdx.x;
    const int wave = tid >> 6;
    const int lane = tid & 63;
    const int col  = lane & 15;
    const int quad = lane >> 4;
    const int v0   = blockIdx.x * 64;
    const int b0   = blockIdx.y * 64;

    short8 wfrag[4];
    #pragma unroll
    for (int mt = 0; mt < 4; ++mt)
        wfrag[mt] = *(const short8*)(whbf + (size_t)(v0 + mt * 16 + col) * 32 + quad * 8);

    float* ts = &Ts[wave][0];
    const int vv = v0 + lane;
    const bool vok = (vv < NUM_VERTS);

    for (int nt = wave; nt < 64; nt += 4) {
        const int b = b0 + nt;
        float* orow = out + (size_t)b * NUM_COORDS + (size_t)vv * 3;
        float h0 = 0.f, h1 = 0.f, h2 = 0.f;
        if (vok) { h0 = orow[0]; h1 = orow[1]; h2 = orow[2]; }

        const short8 bh = *(const short8*)(ahi + ((size_t)b * 16 + col) * 32 + quad * 8);
        const short8 bl = *(const short8*)(alo + ((size_t)b * 16 + col) * 32 + quad * 8);

        f32x4 acc[4];
        #pragma unroll
        for (int mt = 0; mt < 4; ++mt) {
            f32x4 z = {0.f, 0.f, 0.f, 0.f};
            z = __builtin_amdgcn_mfma_f32_16x16x32_bf16(wfrag[mt], bh, z, 0, 0, 0);
            z = __builtin_amdgcn_mfma_f32_16x16x32_bf16(wfrag[mt], bl, z, 0, 0, 0);
            acc[mt] = z;
        }
        #pragma unroll
        for (int mt = 0; mt < 4; ++mt)
            #pragma unroll
            for (int r = 0; r < 4; ++r)
                ts[(mt * 16 + quad * 4 + r) * 20 + col] = acc[mt][r];

        // stride-20 b128 reads: lane*20 dwords = 80 B (16B aligned); banks tile fully
        const f32x4 t0 = *(const f32x4*)(ts + lane * 20 + 0);
        const f32x4 t1 = *(const f32x4*)(ts + lane * 20 + 4);
        const f32x4 t2 = *(const f32x4*)(ts + lane * 20 + 8);

        if (vok) {
            __builtin_nontemporal_store(t0[0] * h0 + t0[1] * h1 + t0[2] * h2 + t0[3], orow + 0);
            __builtin_nontemporal_store(t1[0] * h0 + t1[1] * h1 + t1[2] * h2 + t1[3], orow + 1);
            __builtin_nontemporal_store(t2[0] * h0 + t2[1] * h1 + t2[2] * h2 + t2[3], orow + 2);
        }
    }
}

extern "C" void kernel_launch(void* const* d_in, const int* in_sizes, int n_in,
                              void* d_out, int out_size, void* d_ws, size_t ws_size,
                              hipStream_t stream) {
    const float* x  = (const float*)d_in[0];
    const float* vt = (const float*)d_in[1];
    const float* sd = (const float*)d_in[2];
    const float* Jr = (const float*)d_in[3];
    const float* pd = (const float*)d_in[4];
    const float* w  = (const float*)d_in[5];
    const int* parents = (const int*)d_in[6];
    float* out = (float*)d_out;
    float* ws  = (float*)d_ws;

    k_prep <<<459, 256, 0, stream>>>(Jr, sd, pd, vt, w, ws);
    k_pb   <<<128, 256, 0, stream>>>(x, parents, ws);
    k_gemmA<<<dim3(108, 4), 256, 0, stream>>>(vt, out, ws);
    k_skin <<<dim3(108, 8), 256, 0, stream>>>(out, ws);
}